// Round 4
// baseline (182.644 us; speedup 1.0000x reference)
//
#include <hip/hip_runtime.h>

typedef _Float16 half_t;
typedef _Float16 half2_t __attribute__((ext_vector_type(2)));
typedef _Float16 half4_t __attribute__((ext_vector_type(4)));
typedef _Float16 half8_t __attribute__((ext_vector_type(8)));
typedef float floatx4 __attribute__((ext_vector_type(4)));
typedef float floatx16 __attribute__((ext_vector_type(16)));

#define NE 512
#define NS 16
#define NBATCH 2048
#define NK 64
#define AS 552  // LDS row stride (halves)

// gelu(x) = 0.5 x (1 + erf(x/sqrt2)); erf via A&S 7.1.26 (|err|<=1.5e-7), branch-free.
__device__ __forceinline__ float gelu_erf(float x) {
    float z = x * 0.70710678118654752440f;
    float az2 = z * z;
    float az = __builtin_fabsf(z);
    float t = __builtin_amdgcn_rcpf(__builtin_fmaf(0.3275911f, az, 1.0f));
    float p = __builtin_fmaf(1.061405429f, t, -1.453152027f);
    p = __builtin_fmaf(p, t, 1.421413741f);
    p = __builtin_fmaf(p, t, -0.284496736f);
    p = __builtin_fmaf(p, t, 0.254829592f);
    p = p * t;
    float e = __expf(-az2);
    float erfa = __builtin_fmaf(-p, e, 1.0f);
    unsigned int u = __float_as_uint(erfa) ^ (__float_as_uint(z) & 0x80000000u);
    return 0.5f * x * (1.0f + __uint_as_float(u));
}

__device__ __forceinline__ half4_t cvt4(float4 v) {
    return (half4_t){(half_t)v.x, (half_t)v.y, (half_t)v.z, (half_t)v.w};
}

// packed 32-lane column reduction of 16 values: returns full col-sum of
// x[ln&15] at each lane (reduction over the 32-lane half).
__device__ __forceinline__ float colreduce16(const float (&x)[16], int lnb) {
    float y[8];
#pragma unroll
    for (int i = 0; i < 8; ++i) {
        float keep = (lnb & 1) ? x[2 * i + 1] : x[2 * i];
        float send = (lnb & 1) ? x[2 * i] : x[2 * i + 1];
        y[i] = keep + __shfl_xor(send, 1, 64);
    }
    float z[4];
#pragma unroll
    for (int i = 0; i < 4; ++i) {
        float keep = (lnb & 2) ? y[2 * i + 1] : y[2 * i];
        float send = (lnb & 2) ? y[2 * i] : y[2 * i + 1];
        z[i] = keep + __shfl_xor(send, 2, 64);
    }
    float u[2];
#pragma unroll
    for (int i = 0; i < 2; ++i) {
        float keep = (lnb & 4) ? z[2 * i + 1] : z[2 * i];
        float send = (lnb & 4) ? z[2 * i] : z[2 * i + 1];
        u[i] = keep + __shfl_xor(send, 4, 64);
    }
    float keep = (lnb & 8) ? u[1] : u[0];
    float send = (lnb & 8) ? u[0] : u[1];
    float v = keep + __shfl_xor(send, 8, 64);
    v += __shfl_xor(v, 16, 64);
    return v;
}

// ---------------------------------------------------------------------------
// pack bodies (device): 16x16x32 layout dst[(t*512+n)*32+kk] and 32x32x16
// layout dst[(t*512+n)*16+kk]. Shared tile passed in (max 32*68 halves).
__device__ void pack_w_body(const float* __restrict__ src, half_t* __restrict__ dst,
                            int Ksrc, int t, int nb0, half_t* tile) {
    int tid = threadIdx.x;
#pragma unroll
    for (int i = 0; i < 8; ++i) {
        int idx = tid + i * 256;
        int kk = idx >> 6, np = idx & 63;
        int k = t * 32 + kk;
        float v = (k < Ksrc) ? src[(size_t)k * NE + nb0 + np] : 0.0f;
        tile[kk * 68 + np] = (half_t)v;
    }
    __syncthreads();
#pragma unroll
    for (int i = 0; i < 8; ++i) {
        int idx = tid + i * 256;
        int np = idx >> 5, kk = idx & 31;
        dst[((size_t)t * NE + nb0 + np) * 32 + kk] = tile[kk * 68 + np];
    }
}

__device__ void pack_w32_body(const float* __restrict__ src, half_t* __restrict__ dst,
                              int Ksrc, int t, int nb0, half_t* tile) {
    int tid = threadIdx.x;
#pragma unroll
    for (int i = 0; i < 4; ++i) {
        int idx = tid + i * 256;
        int kk = idx >> 6, n = idx & 63;
        int k = t * 16 + kk;
        float v = (k < Ksrc) ? src[(size_t)k * NE + nb0 + n] : 0.0f;
        tile[kk * 68 + n] = (half_t)v;
    }
    __syncthreads();
    int n = threadIdx.x >> 2, q = threadIdx.x & 3;
    half4_t h = {tile[(q * 4) * 68 + n], tile[(q * 4 + 1) * 68 + n],
                 tile[(q * 4 + 2) * 68 + n], tile[(q * 4 + 3) * 68 + n]};
    *(half4_t*)&dst[((size_t)t * NE + nb0 + n) * 16 + q * 4] = h;
}

// pack_all: one launch does all four weight packs. Block ranges:
// [0,256) Wq | [256,520) Wns (32x32 layout) | [520,656) Wp1 | [656,784) Wp2.
__global__ __launch_bounds__(256) void pack_all(
    const float* __restrict__ sw1, const float* __restrict__ pw1,
    const float* __restrict__ pw2, half_t* __restrict__ Wq,
    half_t* __restrict__ Wns, half_t* __restrict__ Wp1, half_t* __restrict__ Wp2) {
    __shared__ half_t tile[32 * 68];
    int bx = blockIdx.x;
    if (bx < 256) {
        pack_w_body(sw1, Wq, 1024, bx >> 3, (bx & 7) * 64, tile);
    } else if (bx < 520) {
        int b2 = bx - 256;
        pack_w32_body(sw1 + (size_t)1024 * NE, Wns, 528, b2 >> 3, (b2 & 7) * 64, tile);
    } else if (bx < 656) {
        int b3 = bx - 520;
        pack_w_body(pw1, Wp1, 528, b3 >> 3, (b3 & 7) * 64, tile);
    } else {
        int b4 = bx - 656;
        pack_w_body(pw2, Wp2, 512, b4 >> 3, (b4 & 7) * 64, tile);
    }
}

// ---------------------------------------------------------------------------
// qc_kernel: qc[b,n] = q[b]@sw1[0:512] + c[b]@sw1[512:1024] + sb1[n].
// grid = 256: bx>>1 = 16-row group, bx&1 = 256-col half (all CUs busy).
__global__ __launch_bounds__(512) void qc_kernel(const float* __restrict__ q,
                                                 const float* __restrict__ c,
                                                 const half_t* __restrict__ Wq,
                                                 const float* __restrict__ sb1,
                                                 float* __restrict__ qcb) {
    constexpr int AS1 = 1032;
    __shared__ __align__(16) half_t A1[16 * AS1];
    int b0 = (blockIdx.x >> 1) * 16;
    int nh = (blockIdx.x & 1) * 256;
    int tid = threadIdx.x;
#pragma unroll
    for (int i = 0; i < 8; ++i) {
        int f = tid + i * 512;
        int row = f >> 8;
        int c4 = f & 255;
        const float* srcp = (c4 < 128) ? (q + (size_t)(b0 + row) * NE + c4 * 4)
                                       : (c + (size_t)(b0 + row) * NE + (c4 - 128) * 4);
        float4 v = *(const float4*)srcp;
        *(half4_t*)&A1[row * AS1 + c4 * 4] = cvt4(v);
    }
    __syncthreads();
    int w = tid >> 6, l = tid & 63, lg = l >> 4, ln = l & 15;
    floatx4 acc[2] = { {0,0,0,0}, {0,0,0,0} };
    for (int t = 0; t < 32; ++t) {
        half8_t a = *(const half8_t*)&A1[ln * AS1 + t * 32 + 8 * lg];
#pragma unroll
        for (int ni = 0; ni < 2; ++ni) {
            int n = nh + w * 32 + ni * 16 + ln;
            half8_t bf = *(const half8_t*)(Wq + ((size_t)t * NE + n) * 32 + 8 * lg);
            acc[ni] = __builtin_amdgcn_mfma_f32_16x16x32_f16(a, bf, acc[ni], 0, 0, 0);
        }
    }
#pragma unroll
    for (int ni = 0; ni < 2; ++ni) {
        int col = nh + w * 32 + ni * 16 + ln;
        float bias = sb1[col];
#pragma unroll
        for (int r = 0; r < 4; ++r) {
            int row = 4 * lg + r;
            qcb[(size_t)(b0 + row) * NE + col] = acc[ni][r] + bias;
        }
    }
}

// ---------------------------------------------------------------------------
// main_kernel v5: SINGLE-PASS over all 512 cols (wave owns 64 rows x 64 cols,
// acc[2][2] floatx16 = 64 VGPRs) instead of v1's two 32-col passes.
// Rationale: v1 sat at 64 VGPR of the 128/wave budget (4 waves/SIMD); the
// 2-pass split wasted the headroom on a second K-sweep. Single pass:
//  - 4 independent MFMA chains/step (covers dependent-MFMA latency in-wave;
//    v1's 2 chains stalled ~50% per wave and leaned on thin 4-wave TLP),
//  - halves A-tile LDS reads (132 -> 66 ds_read_b128/wave),
//  - one K-sweep: barrier/staging overhead amortized over 2x MFMA,
//  - pass-2 loop + its B-priming deleted.
// B prefetch = rolling 4-slot window (2 loads/step, used 4 steps later; slot
// = s8&3 is STATIC since ch*8 == 0 mod 4 -> no scratch). Staging = 1-ahead:
// issue at iter top, write at iter end (~600 cyc MFMA in between).
// Register budget: acc 64 + B 32 + stage 16 + scal 4 + addr ~8 = ~124 <= 128.
// v2-v4 lessons: 6 waves/SIMD infeasible (85-reg budget < acc+arch);
// any live-state add beyond this budget spills (WRITE_SIZE is the tell).
__global__ __launch_bounds__(512, 4) void main_kernel(
    const float* __restrict__ neighbors, const float* __restrict__ stats,
    const half_t* __restrict__ Wns, const float* __restrict__ qcb,
    const float* __restrict__ sw2, const float* __restrict__ sb2,
    const float* __restrict__ alpha, float* __restrict__ attn_out,
    half_t* __restrict__ mixed) {
    __shared__ __align__(16) half_t A[64 * AS];  // 70656 B
    __shared__ float Llds[64][17];
    __shared__ float attn_s[8][64];              // per-wave copy: no tail barrier

    int b = blockIdx.x;
    int tid = threadIdx.x;
    const float* nb = neighbors + (size_t)b * NK * NE;
    const float* st = stats + (size_t)b * NK * NS;

    int r0 = tid >> 5;     // 0..15 (staging rows r0+16i)
    int c4 = tid & 31;     // float4-col within 128-col chunk
    int w = tid >> 6;      // wave 0..7
    int l = tid & 63, ln = l & 31, hi = l >> 5;
    const half_t* Abase = A + ln * AS + 8 * hi;
    // wave w owns cols [w*64, w*64+63]: tile A = +0, tile B = +32. +t*8192 per K-step.
    const half_t* WbA = Wns + ((size_t)(w * 64 + ln)) * 16 + 8 * hi;
    const half_t* WbB = WbA + 32 * 16;

    float4 s0, s1, s2, s3;
    float qvA, wA, qvB, wB;
    half8_t bfA[4], bfB[4];

    // ---- prologue: stage chunk 0; prime B slots g=0..3; epilogue scalars ----
    {
        float4 p0 = *(const float4*)(nb + (size_t)(r0) * NE + 4 * c4);
        float4 p1 = *(const float4*)(nb + (size_t)(r0 + 16) * NE + 4 * c4);
        float4 p2 = *(const float4*)(nb + (size_t)(r0 + 32) * NE + 4 * c4);
        float4 p3 = *(const float4*)(nb + (size_t)(r0 + 48) * NE + 4 * c4);
        qvA = qcb[(size_t)b * NE + w * 64 + ln];
        wA = sw2[w * 64 + ln];
        qvB = qcb[(size_t)b * NE + w * 64 + 32 + ln];
        wB = sw2[w * 64 + 32 + ln];
#pragma unroll
        for (int s = 0; s < 4; ++s) {
            bfA[s] = *(const half8_t*)(WbA + (size_t)s * 8192);
            bfB[s] = *(const half8_t*)(WbB + (size_t)s * 8192);
        }
        __builtin_amdgcn_sched_barrier(0);
        *(half4_t*)&A[(r0) * AS + 4 * c4] = cvt4(p0);
        *(half4_t*)&A[(r0 + 16) * AS + 4 * c4] = cvt4(p1);
        *(half4_t*)&A[(r0 + 32) * AS + 4 * c4] = cvt4(p2);
        *(half4_t*)&A[(r0 + 48) * AS + 4 * c4] = cvt4(p3);
    }
    asm volatile("s_waitcnt lgkmcnt(0)" ::: "memory");
    __builtin_amdgcn_sched_barrier(0);
    __builtin_amdgcn_s_barrier();
    __builtin_amdgcn_sched_barrier(0);

    floatx16 acc00 = {0,0,0,0,0,0,0,0,0,0,0,0,0,0,0,0};
    floatx16 acc01 = {0,0,0,0,0,0,0,0,0,0,0,0,0,0,0,0};
    floatx16 acc10 = {0,0,0,0,0,0,0,0,0,0,0,0,0,0,0,0};
    floatx16 acc11 = {0,0,0,0,0,0,0,0,0,0,0,0,0,0,0,0};

    // ---- chunks 0..2: stage-issue at top, 8 K-steps, write+barrier at end ----
#pragma unroll 1
    for (int ch = 0; ch < 3; ++ch) {
        // issue next chunk's staging loads (consumed at iter end, ~600cy away)
        s0 = *(const float4*)(nb + (size_t)(r0) * NE + (ch + 1) * 128 + 4 * c4);
        s1 = *(const float4*)(nb + (size_t)(r0 + 16) * NE + (ch + 1) * 128 + 4 * c4);
        s2 = *(const float4*)(nb + (size_t)(r0 + 32) * NE + (ch + 1) * 128 + 4 * c4);
        s3 = *(const float4*)(nb + (size_t)(r0 + 48) * NE + (ch + 1) * 128 + 4 * c4);
        __builtin_amdgcn_sched_barrier(0);
#pragma unroll
        for (int s8 = 0; s8 < 8; ++s8) {
            const int slot = s8 & 3;                 // ch*8 == 0 mod 4 -> static
            half8_t bA = bfA[slot], bB = bfB[slot];
            // refill slot with step g+4 (always exists for ch<3: g+4 <= 27)
            bfA[slot] = *(const half8_t*)(WbA + (size_t)(ch * 8 + s8 + 4) * 8192);
            bfB[slot] = *(const half8_t*)(WbB + (size_t)(ch * 8 + s8 + 4) * 8192);
            int col = ch * 128 + s8 * 16;
            half8_t a0 = *(const half8_t*)&Abase[col];
            half8_t a1 = *(const half8_t*)&Abase[32 * AS + col];
            acc00 = __builtin_amdgcn_mfma_f32_32x32x16_f16(a0, bA, acc00, 0, 0, 0);
            acc10 = __builtin_amdgcn_mfma_f32_32x32x16_f16(a1, bA, acc10, 0, 0, 0);
            acc01 = __builtin_amdgcn_mfma_f32_32x32x16_f16(a0, bB, acc01, 0, 0, 0);
            acc11 = __builtin_amdgcn_mfma_f32_32x32x16_f16(a1, bB, acc11, 0, 0, 0);
        }
        __builtin_amdgcn_sched_barrier(0);
        *(half4_t*)&A[(r0) * AS + (ch + 1) * 128 + 4 * c4] = cvt4(s0);
        *(half4_t*)&A[(r0 + 16) * AS + (ch + 1) * 128 + 4 * c4] = cvt4(s1);
        *(half4_t*)&A[(r0 + 32) * AS + (ch + 1) * 128 + 4 * c4] = cvt4(s2);
        *(half4_t*)&A[(r0 + 48) * AS + (ch + 1) * 128 + 4 * c4] = cvt4(s3);
        asm volatile("s_waitcnt lgkmcnt(0)" ::: "memory");
        __builtin_amdgcn_sched_barrier(0);
        __builtin_amdgcn_s_barrier();
        __builtin_amdgcn_sched_barrier(0);
    }

    // ---- chunk 3: stats staged via s0; refill only while g+4 <= 32 ----
    {
        if (tid < 256)
            s0 = *(const float4*)(st + (tid >> 2) * NS + (tid & 3) * 4);
        __builtin_amdgcn_sched_barrier(0);
#pragma unroll
        for (int s8 = 0; s8 < 8; ++s8) {
            const int slot = s8 & 3;
            half8_t bA = bfA[slot], bB = bfB[slot];
            if (s8 <= 4) {  // g = 24+s8; refill g+4 = 28..32 (static condition)
                bfA[slot] = *(const half8_t*)(WbA + (size_t)(28 + s8) * 8192);
                bfB[slot] = *(const half8_t*)(WbB + (size_t)(28 + s8) * 8192);
            }
            int col = 3 * 128 + s8 * 16;
            half8_t a0 = *(const half8_t*)&Abase[col];
            half8_t a1 = *(const half8_t*)&Abase[32 * AS + col];
            acc00 = __builtin_amdgcn_mfma_f32_32x32x16_f16(a0, bA, acc00, 0, 0, 0);
            acc10 = __builtin_amdgcn_mfma_f32_32x32x16_f16(a1, bA, acc10, 0, 0, 0);
            acc01 = __builtin_amdgcn_mfma_f32_32x32x16_f16(a0, bB, acc01, 0, 0, 0);
            acc11 = __builtin_amdgcn_mfma_f32_32x32x16_f16(a1, bB, acc11, 0, 0, 0);
        }
        __builtin_amdgcn_sched_barrier(0);
        if (tid < 256)
            *(half4_t*)&A[(tid >> 2) * AS + 512 + (tid & 3) * 4] = cvt4(s0);
        asm volatile("s_waitcnt lgkmcnt(0)" ::: "memory");
        __builtin_amdgcn_sched_barrier(0);
        __builtin_amdgcn_s_barrier();
        __builtin_amdgcn_sched_barrier(0);
    }
    // K-tail: stats cols 512..527 (t = 32, in slot 0 -- refilled at s8==4)
    {
        half8_t a0 = *(const half8_t*)&Abase[512];
        half8_t a1 = *(const half8_t*)&Abase[32 * AS + 512];
        acc00 = __builtin_amdgcn_mfma_f32_32x32x16_f16(a0, bfA[0], acc00, 0, 0, 0);
        acc10 = __builtin_amdgcn_mfma_f32_32x32x16_f16(a1, bfA[0], acc10, 0, 0, 0);
        acc01 = __builtin_amdgcn_mfma_f32_32x32x16_f16(a0, bfB[0], acc01, 0, 0, 0);
        acc11 = __builtin_amdgcn_mfma_f32_32x32x16_f16(a1, bfB[0], acc11, 0, 0, 0);
    }

    // ---- single epilogue: 64 gelu + 4 colreduce; col-group of tileA = 2w,
    //      tileB = 2w+1; rows 0-31 -> Llds[row], rows 32-63 -> Llds[32+row] ----
    {
        float g0[16];
#pragma unroll
        for (int r = 0; r < 16; ++r) g0[r] = gelu_erf(acc00[r] + qvA) * wA;
        float rA = colreduce16(g0, ln);
#pragma unroll
        for (int r = 0; r < 16; ++r) g0[r] = gelu_erf(acc01[r] + qvB) * wB;
        float rB = colreduce16(g0, ln);
        if (ln < 16) {
            int row = (ln & 3) + 8 * (ln >> 2) + 4 * hi;
            Llds[row][2 * w] = rA;
            Llds[row][2 * w + 1] = rB;
        }
#pragma unroll
        for (int r = 0; r < 16; ++r) g0[r] = gelu_erf(acc10[r] + qvA) * wA;
        rA = colreduce16(g0, ln);
#pragma unroll
        for (int r = 0; r < 16; ++r) g0[r] = gelu_erf(acc11[r] + qvB) * wB;
        rB = colreduce16(g0, ln);
        if (ln < 16) {
            int row = (ln & 3) + 8 * (ln >> 2) + 4 * hi;
            Llds[32 + row][2 * w] = rA;
            Llds[32 + row][2 * w + 1] = rB;
        }
    }
    __syncthreads();   // Llds is cross-wave: barrier required

    // ---- softmax over K=64: ALL waves redundantly; lane l owns k=l ----
    {
        int k = l;
        float lsum = 0.0f;
#pragma unroll
        for (int j = 0; j < 16; ++j) lsum += Llds[k][j];
        float sim = st[k * NS + (NS - 1)];
        float logit = lsum + sb2[0] + alpha[0] * sim;
        float mx = logit;
#pragma unroll
        for (int m = 1; m < 64; m <<= 1) mx = fmaxf(mx, __shfl_xor(mx, m, 64));
        float e = __expf(logit - mx);
        float s = e;
#pragma unroll
        for (int m = 1; m < 64; m <<= 1) s += __shfl_xor(s, m, 64);
        float at = e / s;
        attn_s[w][k] = at;                 // own wave's copy: DS in-order
        if (w == 0) attn_out[(size_t)b * NK + k] = at;
    }
    // NO barrier: each wave reads only its own attn_s[w] copy below.

    // ---- mix from LDS (half2 per thread): mixed[e'] = sum_k attn[k]*A[k][e'] ----
    if (tid < 264) {
        int c0 = 2 * tid;  // cols [c0, c0+1], covers 0..527 (real data only)
        float m0 = 0.0f, m1 = 0.0f;
#pragma unroll 8
        for (int k = 0; k < NK; ++k) {
            half2_t v = *(const half2_t*)&A[k * AS + c0];
            float aw = attn_s[w][k];
            m0 += aw * (float)v[0];
            m1 += aw * (float)v[1];
        }
        *(half2_t*)&mixed[(size_t)b * AS + c0] = (half2_t){(half_t)m0, (half_t)m1};
    } else if (tid < 270) {
        int z = tid - 264;  // zero cols 528..551 (6 x half4)
        half4_t hz = {};
        *(half4_t*)&mixed[(size_t)b * AS + 528 + 4 * z] = hz;
    }
}

// ---------------------------------------------------------------------------
// proj_kernel: out = gelu(mixed@pw1 + pb1) @ pw2 + pb2, both layers fused.
// 1024 threads = 16 waves (wave owns 32 cols) for better latency hiding.
__global__ __launch_bounds__(1024) void proj_kernel(
    const half_t* __restrict__ mixedp, const half_t* __restrict__ Wp1,
    const half_t* __restrict__ Wp2, const float* __restrict__ pb1,
    const float* __restrict__ pb2, float* __restrict__ out) {
    constexpr int AS3 = AS;
    __shared__ __align__(16) half_t A1[16 * AS3];
    int b0 = blockIdx.x * 16;
    int tid = threadIdx.x;
    const uint4* src = (const uint4*)(mixedp + (size_t)b0 * AS3);
    for (int i = tid; i < 1104; i += 1024) ((uint4*)A1)[i] = src[i];
    __syncthreads();

    int w = tid >> 6, l = tid & 63, lg = l >> 4, ln = l & 15;
    floatx4 acc[2] = { {0,0,0,0}, {0,0,0,0} };
    for (int t = 0; t < 17; ++t) {
        half8_t a = *(const half8_t*)&A1[ln * AS3 + t * 32 + 8 * lg];
#pragma unroll
        for (int ni = 0; ni < 2; ++ni) {
            int n = w * 32 + ni * 16 + ln;
            half8_t bf = *(const half8_t*)(Wp1 + ((size_t)t * NE + n) * 32 + 8 * lg);
            acc[ni] = __builtin_amdgcn_mfma_f32_16x16x32_f16(a, bf, acc[ni], 0, 0, 0);
        }
    }
    __syncthreads();
#pragma unroll
    for (int ni = 0; ni < 2; ++ni) {
        int col = w * 32 + ni * 16 + ln;
        float bias = pb1[col];
#pragma unroll
        for (int r = 0; r < 4; ++r) {
            int row = 4 * lg + r;
            A1[row * AS3 + col] = (half_t)gelu_erf(acc[ni][r] + bias);
        }
    }
    __syncthreads();
    floatx4 acc2[2] = { {0,0,0,0}, {0,0,0,0} };
    for (int t = 0; t < 16; ++t) {
        half8_t a = *(const half8_t*)&A1[ln * AS3 + t * 32 + 8 * lg];
#pragma unroll
        for (int ni = 0; ni < 2; ++ni) {
            int n = w * 32 + ni * 16 + ln;
            half8_t bf = *(const half8_t*)(Wp2 + ((size_t)t * NE + n) * 32 + 8 * lg);
            acc2[ni] = __builtin_amdgcn_mfma_f32_16x16x32_f16(a, bf, acc2[ni], 0, 0, 0);
        }
    }
#pragma unroll
    for (int ni = 0; ni < 2; ++ni) {
        int col = w * 32 + ni * 16 + ln;
        float bias = pb2[col];
#pragma unroll
        for (int r = 0; r < 4; ++r)
            out[(size_t)(b0 + 4 * lg + r) * NE + col] = acc2[ni][r] + bias;
    }
}

// ---------------------------------------------------------------------------
extern "C" void kernel_launch(void* const* d_in, const int* in_sizes, int n_in,
                              void* d_out, int out_size, void* d_ws, size_t ws_size,
                              hipStream_t stream) {
    (void)in_sizes; (void)n_in; (void)out_size; (void)ws_size;
    const float* q     = (const float*)d_in[0];
    const float* c     = (const float*)d_in[1];
    const float* nb    = (const float*)d_in[2];
    const float* st    = (const float*)d_in[3];
    const float* sw1   = (const float*)d_in[4];
    const float* sb1   = (const float*)d_in[5];
    const float* sw2   = (const float*)d_in[6];
    const float* sb2   = (const float*)d_in[7];
    const float* alpha = (const float*)d_in[8];
    const float* pw1   = (const float*)d_in[9];
    const float* pb1   = (const float*)d_in[10];
    const float* pw2   = (const float*)d_in[11];
    const float* pb2   = (const float*)d_in[12];

    char* ws = (char*)d_ws;
    half_t* Wq  = (half_t*)(ws + 0);          // 1024*512*2 = 1048576
    half_t* Wns = (half_t*)(ws + 1048576);    // 33*512*16*2 = 540672
    half_t* Wp1 = (half_t*)(ws + 1605632);    // 544*512*2  = 557056
    half_t* Wp2 = (half_t*)(ws + 2162688);    // 512*512*2  = 524288
    float*  qcb = (float*)(ws + 2686976);     // 2048*512*4 = 4194304
    half_t* mix = (half_t*)(ws + 6881280);    // 2048*552*2 = 2260992

    float* outp  = (float*)d_out;
    float* attnp = outp + (size_t)NBATCH * NE;

    pack_all<<<784, 256, 0, stream>>>(sw1, pw1, pw2, Wq, Wns, Wp1, Wp2);
    qc_kernel<<<256, 512, 0, stream>>>(q, c, Wq, sb1, qcb);
    main_kernel<<<2048, 512, 0, stream>>>(nb, st, Wns, qcb, sw2, sb2, alpha, attnp, mix);
    proj_kernel<<<128, 1024, 0, stream>>>(mix, Wp1, Wp2, pb1, pb2, outp);
}

// Round 5
// 179.426 us; speedup vs baseline: 1.0179x; 1.0179x over previous
//
#include <hip/hip_runtime.h>

typedef _Float16 half_t;
typedef _Float16 half2_t __attribute__((ext_vector_type(2)));
typedef _Float16 half4_t __attribute__((ext_vector_type(4)));
typedef _Float16 half8_t __attribute__((ext_vector_type(8)));
typedef float floatx4 __attribute__((ext_vector_type(4)));
typedef float floatx16 __attribute__((ext_vector_type(16)));

#define NE 512
#define NS 16
#define NBATCH 2048
#define NK 64
#define AS 552  // LDS row stride (halves)

// gelu(x) = 0.5 x (1 + erf(x/sqrt2)); erf via A&S 7.1.26 (|err|<=1.5e-7), branch-free.
__device__ __forceinline__ float gelu_erf(float x) {
    float z = x * 0.70710678118654752440f;
    float az2 = z * z;
    float az = __builtin_fabsf(z);
    float t = __builtin_amdgcn_rcpf(__builtin_fmaf(0.3275911f, az, 1.0f));
    float p = __builtin_fmaf(1.061405429f, t, -1.453152027f);
    p = __builtin_fmaf(p, t, 1.421413741f);
    p = __builtin_fmaf(p, t, -0.284496736f);
    p = __builtin_fmaf(p, t, 0.254829592f);
    p = p * t;
    float e = __expf(-az2);
    float erfa = __builtin_fmaf(-p, e, 1.0f);
    unsigned int u = __float_as_uint(erfa) ^ (__float_as_uint(z) & 0x80000000u);
    return 0.5f * x * (1.0f + __uint_as_float(u));
}

__device__ __forceinline__ half4_t cvt4(float4 v) {
    return (half4_t){(half_t)v.x, (half_t)v.y, (half_t)v.z, (half_t)v.w};
}

// packed 32-lane column reduction of 16 values: returns full col-sum of
// x[ln&15] at each lane (reduction over the 32-lane half).
__device__ __forceinline__ float colreduce16(const float (&x)[16], int lnb) {
    float y[8];
#pragma unroll
    for (int i = 0; i < 8; ++i) {
        float keep = (lnb & 1) ? x[2 * i + 1] : x[2 * i];
        float send = (lnb & 1) ? x[2 * i] : x[2 * i + 1];
        y[i] = keep + __shfl_xor(send, 1, 64);
    }
    float z[4];
#pragma unroll
    for (int i = 0; i < 4; ++i) {
        float keep = (lnb & 2) ? y[2 * i + 1] : y[2 * i];
        float send = (lnb & 2) ? y[2 * i] : y[2 * i + 1];
        z[i] = keep + __shfl_xor(send, 2, 64);
    }
    float u[2];
#pragma unroll
    for (int i = 0; i < 2; ++i) {
        float keep = (lnb & 4) ? z[2 * i + 1] : z[2 * i];
        float send = (lnb & 4) ? z[2 * i] : z[2 * i + 1];
        u[i] = keep + __shfl_xor(send, 4, 64);
    }
    float keep = (lnb & 8) ? u[1] : u[0];
    float send = (lnb & 8) ? u[0] : u[1];
    float v = keep + __shfl_xor(send, 8, 64);
    v += __shfl_xor(v, 16, 64);
    return v;
}

// epilogue helper: gelu+scale 16 values of one 32x32 acc tile, col-reduce,
// store per-row partial into Llds[rowofs+row][cg].
__device__ __forceinline__ void epi_one(const floatx16& acc, float qv, float w2,
                                        int rowofs, int cg, int ln, int hi,
                                        float (*Llds)[17]) {
    float g[16];
#pragma unroll
    for (int r = 0; r < 16; ++r) g[r] = gelu_erf(acc[r] + qv) * w2;
    float rr = colreduce16(g, ln);
    if (ln < 16) {
        int row = (ln & 3) + 8 * (ln >> 2) + 4 * hi;
        Llds[rowofs + row][cg] = rr;
    }
}

// ---------------------------------------------------------------------------
// pack bodies (device): 16x16x32 layout dst[(t*512+n)*32+kk] and 32x32x16
// layout dst[(t*512+n)*16+kk]. Shared tile passed in (max 32*68 halves).
__device__ void pack_w_body(const float* __restrict__ src, half_t* __restrict__ dst,
                            int Ksrc, int t, int nb0, half_t* tile) {
    int tid = threadIdx.x;
#pragma unroll
    for (int i = 0; i < 8; ++i) {
        int idx = tid + i * 256;
        int kk = idx >> 6, np = idx & 63;
        int k = t * 32 + kk;
        float v = (k < Ksrc) ? src[(size_t)k * NE + nb0 + np] : 0.0f;
        tile[kk * 68 + np] = (half_t)v;
    }
    __syncthreads();
#pragma unroll
    for (int i = 0; i < 8; ++i) {
        int idx = tid + i * 256;
        int np = idx >> 5, kk = idx & 31;
        dst[((size_t)t * NE + nb0 + np) * 32 + kk] = tile[kk * 68 + np];
    }
}

__device__ void pack_w32_body(const float* __restrict__ src, half_t* __restrict__ dst,
                              int Ksrc, int t, int nb0, half_t* tile) {
    int tid = threadIdx.x;
#pragma unroll
    for (int i = 0; i < 4; ++i) {
        int idx = tid + i * 256;
        int kk = idx >> 6, n = idx & 63;
        int k = t * 16 + kk;
        float v = (k < Ksrc) ? src[(size_t)k * NE + nb0 + n] : 0.0f;
        tile[kk * 68 + n] = (half_t)v;
    }
    __syncthreads();
    int n = threadIdx.x >> 2, q = threadIdx.x & 3;
    half4_t h = {tile[(q * 4) * 68 + n], tile[(q * 4 + 1) * 68 + n],
                 tile[(q * 4 + 2) * 68 + n], tile[(q * 4 + 3) * 68 + n]};
    *(half4_t*)&dst[((size_t)t * NE + nb0 + n) * 16 + q * 4] = h;
}

// pack_all: one launch does all four weight packs. Block ranges:
// [0,256) Wq | [256,520) Wns (32x32 layout) | [520,656) Wp1 | [656,784) Wp2.
__global__ __launch_bounds__(256) void pack_all(
    const float* __restrict__ sw1, const float* __restrict__ pw1,
    const float* __restrict__ pw2, half_t* __restrict__ Wq,
    half_t* __restrict__ Wns, half_t* __restrict__ Wp1, half_t* __restrict__ Wp2) {
    __shared__ half_t tile[32 * 68];
    int bx = blockIdx.x;
    if (bx < 256) {
        pack_w_body(sw1, Wq, 1024, bx >> 3, (bx & 7) * 64, tile);
    } else if (bx < 520) {
        int b2 = bx - 256;
        pack_w32_body(sw1 + (size_t)1024 * NE, Wns, 528, b2 >> 3, (b2 & 7) * 64, tile);
    } else if (bx < 656) {
        int b3 = bx - 520;
        pack_w_body(pw1, Wp1, 528, b3 >> 3, (b3 & 7) * 64, tile);
    } else {
        int b4 = bx - 656;
        pack_w_body(pw2, Wp2, 512, b4 >> 3, (b4 & 7) * 64, tile);
    }
}

// ---------------------------------------------------------------------------
// qc_kernel: qc[b,n] = q[b]@sw1[0:512] + c[b]@sw1[512:1024] + sb1[n].
// grid = 256: bx>>1 = 16-row group, bx&1 = 256-col half (all CUs busy).
__global__ __launch_bounds__(512) void qc_kernel(const float* __restrict__ q,
                                                 const float* __restrict__ c,
                                                 const half_t* __restrict__ Wq,
                                                 const float* __restrict__ sb1,
                                                 float* __restrict__ qcb) {
    constexpr int AS1 = 1032;
    __shared__ __align__(16) half_t A1[16 * AS1];
    int b0 = (blockIdx.x >> 1) * 16;
    int nh = (blockIdx.x & 1) * 256;
    int tid = threadIdx.x;
#pragma unroll
    for (int i = 0; i < 8; ++i) {
        int f = tid + i * 512;
        int row = f >> 8;
        int c4 = f & 255;
        const float* srcp = (c4 < 128) ? (q + (size_t)(b0 + row) * NE + c4 * 4)
                                       : (c + (size_t)(b0 + row) * NE + (c4 - 128) * 4);
        float4 v = *(const float4*)srcp;
        *(half4_t*)&A1[row * AS1 + c4 * 4] = cvt4(v);
    }
    __syncthreads();
    int w = tid >> 6, l = tid & 63, lg = l >> 4, ln = l & 15;
    floatx4 acc[2] = { {0,0,0,0}, {0,0,0,0} };
    for (int t = 0; t < 32; ++t) {
        half8_t a = *(const half8_t*)&A1[ln * AS1 + t * 32 + 8 * lg];
#pragma unroll
        for (int ni = 0; ni < 2; ++ni) {
            int n = nh + w * 32 + ni * 16 + ln;
            half8_t bf = *(const half8_t*)(Wq + ((size_t)t * NE + n) * 32 + 8 * lg);
            acc[ni] = __builtin_amdgcn_mfma_f32_16x16x32_f16(a, bf, acc[ni], 0, 0, 0);
        }
    }
#pragma unroll
    for (int ni = 0; ni < 2; ++ni) {
        int col = nh + w * 32 + ni * 16 + ln;
        float bias = sb1[col];
#pragma unroll
        for (int r = 0; r < 4; ++r) {
            int row = 4 * lg + r;
            qcb[(size_t)(b0 + row) * NE + col] = acc[ni][r] + bias;
        }
    }
}

// ---------------------------------------------------------------------------
// main_kernel v6: FAT WAVES. 256 threads = 4 waves, each wave owns 64 rows x
// 128 cols (acc = 8 x floatx16 = 128 regs). 2 blocks/CU (LDS 152/160 KB) =
// 8 waves/CU = 2 waves/SIMD -> 256-reg/wave budget (v1-v5 lesson: 512-thread
// blocks cap at 128 regs and anything past v1's acc-32 2-pass design spills).
// Latency hiding moves from TLP to ILP: 8 independent MFMA chains per K-step
// from 2 A-frag reads (v1: 2 chains / 2 reads) -- 4x fewer A LDS reads, one
// single K-sweep (half the barriers), no pass-2 machinery.
// B = double-set (bX/bY) refilled 2 steps ahead; A staged 1 chunk ahead in 8
// float4. Peak regs ~= acc 128 + B 32 + stage 32 + temps/addr ~40 = ~232.
// WRITE_SIZE is the spill gate: ~2.7 MB = clean, tens of MB = spilled.
__global__ __launch_bounds__(256, 2) void main_kernel(
    const float* __restrict__ neighbors, const float* __restrict__ stats,
    const half_t* __restrict__ Wns, const float* __restrict__ qcb,
    const float* __restrict__ sw2, const float* __restrict__ sb2,
    const float* __restrict__ alpha, float* __restrict__ attn_out,
    half_t* __restrict__ mixed) {
    __shared__ __align__(16) half_t A[64 * AS];  // 70656 B
    __shared__ float Llds[64][17];               // 4352 B
    __shared__ float attn_s[4][64];              // 1024 B

    int b = blockIdx.x;
    int tid = threadIdx.x;
    const float* nb = neighbors + (size_t)b * NK * NE;
    const float* st = stats + (size_t)b * NK * NS;

    int r0 = tid >> 4;     // 0..15 (staging rows r0+16i)
    int c4 = tid & 15;     // float4-col within 64-col half-chunk
    int w = tid >> 6;      // wave 0..3
    int l = tid & 63, ln = l & 31, hi = l >> 5;
    const half_t* Abase = A + ln * AS + 8 * hi;
    // wave w owns cols [w*128, w*128+128): col-tile c at +c*512 halves, +t*8192 per K-step
    const half_t* Wb = Wns + ((size_t)(w * 128 + ln)) * 16 + 8 * hi;

    float4 s0, s1, s2, s3, s4, s5, s6, s7;
    float qv0, qv1, qv2, qv3, w20, w21, w22, w23;
    half8_t bx0, bx1, bx2, bx3, by0, by1, by2, by3;

    // ---- prologue: stage chunk 0 (both 64-col halves); B sets t=0/1;
    //      epilogue scalars; issue chunk 1 ----
    {
        float4 p0 = *(const float4*)(nb + (size_t)(r0) * NE + 4 * c4);
        float4 p1 = *(const float4*)(nb + (size_t)(r0 + 16) * NE + 4 * c4);
        float4 p2 = *(const float4*)(nb + (size_t)(r0 + 32) * NE + 4 * c4);
        float4 p3 = *(const float4*)(nb + (size_t)(r0 + 48) * NE + 4 * c4);
        float4 p4 = *(const float4*)(nb + (size_t)(r0) * NE + 64 + 4 * c4);
        float4 p5 = *(const float4*)(nb + (size_t)(r0 + 16) * NE + 64 + 4 * c4);
        float4 p6 = *(const float4*)(nb + (size_t)(r0 + 32) * NE + 64 + 4 * c4);
        float4 p7 = *(const float4*)(nb + (size_t)(r0 + 48) * NE + 64 + 4 * c4);
        qv0 = qcb[(size_t)b * NE + w * 128 + ln];
        qv1 = qcb[(size_t)b * NE + w * 128 + 32 + ln];
        qv2 = qcb[(size_t)b * NE + w * 128 + 64 + ln];
        qv3 = qcb[(size_t)b * NE + w * 128 + 96 + ln];
        w20 = sw2[w * 128 + ln];
        w21 = sw2[w * 128 + 32 + ln];
        w22 = sw2[w * 128 + 64 + ln];
        w23 = sw2[w * 128 + 96 + ln];
        bx0 = *(const half8_t*)(Wb);
        bx1 = *(const half8_t*)(Wb + 512);
        bx2 = *(const half8_t*)(Wb + 1024);
        bx3 = *(const half8_t*)(Wb + 1536);
        by0 = *(const half8_t*)(Wb + 8192);
        by1 = *(const half8_t*)(Wb + 8192 + 512);
        by2 = *(const half8_t*)(Wb + 8192 + 1024);
        by3 = *(const half8_t*)(Wb + 8192 + 1536);
        __builtin_amdgcn_sched_barrier(0);
        *(half4_t*)&A[(r0) * AS + 4 * c4] = cvt4(p0);
        *(half4_t*)&A[(r0 + 16) * AS + 4 * c4] = cvt4(p1);
        *(half4_t*)&A[(r0 + 32) * AS + 4 * c4] = cvt4(p2);
        *(half4_t*)&A[(r0 + 48) * AS + 4 * c4] = cvt4(p3);
        *(half4_t*)&A[(r0) * AS + 64 + 4 * c4] = cvt4(p4);
        *(half4_t*)&A[(r0 + 16) * AS + 64 + 4 * c4] = cvt4(p5);
        *(half4_t*)&A[(r0 + 32) * AS + 64 + 4 * c4] = cvt4(p6);
        *(half4_t*)&A[(r0 + 48) * AS + 64 + 4 * c4] = cvt4(p7);
        __builtin_amdgcn_sched_barrier(0);
        s0 = *(const float4*)(nb + (size_t)(r0) * NE + 128 + 4 * c4);
        s1 = *(const float4*)(nb + (size_t)(r0 + 16) * NE + 128 + 4 * c4);
        s2 = *(const float4*)(nb + (size_t)(r0 + 32) * NE + 128 + 4 * c4);
        s3 = *(const float4*)(nb + (size_t)(r0 + 48) * NE + 128 + 4 * c4);
        s4 = *(const float4*)(nb + (size_t)(r0) * NE + 192 + 4 * c4);
        s5 = *(const float4*)(nb + (size_t)(r0 + 16) * NE + 192 + 4 * c4);
        s6 = *(const float4*)(nb + (size_t)(r0 + 32) * NE + 192 + 4 * c4);
        s7 = *(const float4*)(nb + (size_t)(r0 + 48) * NE + 192 + 4 * c4);
    }
    asm volatile("s_waitcnt lgkmcnt(0)" ::: "memory");
    __builtin_amdgcn_sched_barrier(0);
    __builtin_amdgcn_s_barrier();
    __builtin_amdgcn_sched_barrier(0);

    floatx16 acc00 = {0,0,0,0,0,0,0,0,0,0,0,0,0,0,0,0};
    floatx16 acc01 = {0,0,0,0,0,0,0,0,0,0,0,0,0,0,0,0};
    floatx16 acc02 = {0,0,0,0,0,0,0,0,0,0,0,0,0,0,0,0};
    floatx16 acc03 = {0,0,0,0,0,0,0,0,0,0,0,0,0,0,0,0};
    floatx16 acc10 = {0,0,0,0,0,0,0,0,0,0,0,0,0,0,0,0};
    floatx16 acc11 = {0,0,0,0,0,0,0,0,0,0,0,0,0,0,0,0};
    floatx16 acc12 = {0,0,0,0,0,0,0,0,0,0,0,0,0,0,0,0};
    floatx16 acc13 = {0,0,0,0,0,0,0,0,0,0,0,0,0,0,0,0};

    // ---- single K-sweep: 4 chunks x 8 steps (t = 0..31), tail t=32 ----
#pragma unroll 1
    for (int ch = 0; ch < 4; ++ch) {
#pragma unroll
        for (int s2i = 0; s2i < 4; ++s2i) {
            // even step te: uses bX, refills bX with t = te+2
            {
                int te = ch * 8 + 2 * s2i;
                int col = te * 16;
                half8_t a0 = *(const half8_t*)&Abase[col];
                half8_t a1 = *(const half8_t*)&Abase[32 * AS + col];
                acc00 = __builtin_amdgcn_mfma_f32_32x32x16_f16(a0, bx0, acc00, 0, 0, 0);
                acc10 = __builtin_amdgcn_mfma_f32_32x32x16_f16(a1, bx0, acc10, 0, 0, 0);
                acc01 = __builtin_amdgcn_mfma_f32_32x32x16_f16(a0, bx1, acc01, 0, 0, 0);
                acc11 = __builtin_amdgcn_mfma_f32_32x32x16_f16(a1, bx1, acc11, 0, 0, 0);
                acc02 = __builtin_amdgcn_mfma_f32_32x32x16_f16(a0, bx2, acc02, 0, 0, 0);
                acc12 = __builtin_amdgcn_mfma_f32_32x32x16_f16(a1, bx2, acc12, 0, 0, 0);
                acc03 = __builtin_amdgcn_mfma_f32_32x32x16_f16(a0, bx3, acc03, 0, 0, 0);
                acc13 = __builtin_amdgcn_mfma_f32_32x32x16_f16(a1, bx3, acc13, 0, 0, 0);
                int tn = te + 2; if (tn > 32) tn = 32;
                const half_t* Wt = Wb + (size_t)tn * 8192;
                bx0 = *(const half8_t*)(Wt);
                bx1 = *(const half8_t*)(Wt + 512);
                bx2 = *(const half8_t*)(Wt + 1024);
                bx3 = *(const half8_t*)(Wt + 1536);
            }
            // odd step to: uses bY, refills bY with t = to+2
            {
                int to = ch * 8 + 2 * s2i + 1;
                int col = to * 16;
                half8_t a0 = *(const half8_t*)&Abase[col];
                half8_t a1 = *(const half8_t*)&Abase[32 * AS + col];
                acc00 = __builtin_amdgcn_mfma_f32_32x32x16_f16(a0, by0, acc00, 0, 0, 0);
                acc10 = __builtin_amdgcn_mfma_f32_32x32x16_f16(a1, by0, acc10, 0, 0, 0);
                acc01 = __builtin_amdgcn_mfma_f32_32x32x16_f16(a0, by1, acc01, 0, 0, 0);
                acc11 = __builtin_amdgcn_mfma_f32_32x32x16_f16(a1, by1, acc11, 0, 0, 0);
                acc02 = __builtin_amdgcn_mfma_f32_32x32x16_f16(a0, by2, acc02, 0, 0, 0);
                acc12 = __builtin_amdgcn_mfma_f32_32x32x16_f16(a1, by2, acc12, 0, 0, 0);
                acc03 = __builtin_amdgcn_mfma_f32_32x32x16_f16(a0, by3, acc03, 0, 0, 0);
                acc13 = __builtin_amdgcn_mfma_f32_32x32x16_f16(a1, by3, acc13, 0, 0, 0);
                int tn = to + 2; if (tn > 32) tn = 32;
                const half_t* Wt = Wb + (size_t)tn * 8192;
                by0 = *(const half8_t*)(Wt);
                by1 = *(const half8_t*)(Wt + 512);
                by2 = *(const half8_t*)(Wt + 1024);
                by3 = *(const half8_t*)(Wt + 1536);
            }
        }
        __builtin_amdgcn_sched_barrier(0);
        if (ch < 3) {
            int cb = (ch + 1) * 128;
            *(half4_t*)&A[(r0) * AS + cb + 4 * c4] = cvt4(s0);
            *(half4_t*)&A[(r0 + 16) * AS + cb + 4 * c4] = cvt4(s1);
            *(half4_t*)&A[(r0 + 32) * AS + cb + 4 * c4] = cvt4(s2);
            *(half4_t*)&A[(r0 + 48) * AS + cb + 4 * c4] = cvt4(s3);
            *(half4_t*)&A[(r0) * AS + cb + 64 + 4 * c4] = cvt4(s4);
            *(half4_t*)&A[(r0 + 16) * AS + cb + 64 + 4 * c4] = cvt4(s5);
            *(half4_t*)&A[(r0 + 32) * AS + cb + 64 + 4 * c4] = cvt4(s6);
            *(half4_t*)&A[(r0 + 48) * AS + cb + 64 + 4 * c4] = cvt4(s7);
            __builtin_amdgcn_sched_barrier(0);
            if (ch < 2) {
                int nc = (ch + 2) * 128;
                s0 = *(const float4*)(nb + (size_t)(r0) * NE + nc + 4 * c4);
                s1 = *(const float4*)(nb + (size_t)(r0 + 16) * NE + nc + 4 * c4);
                s2 = *(const float4*)(nb + (size_t)(r0 + 32) * NE + nc + 4 * c4);
                s3 = *(const float4*)(nb + (size_t)(r0 + 48) * NE + nc + 4 * c4);
                s4 = *(const float4*)(nb + (size_t)(r0) * NE + nc + 64 + 4 * c4);
                s5 = *(const float4*)(nb + (size_t)(r0 + 16) * NE + nc + 64 + 4 * c4);
                s6 = *(const float4*)(nb + (size_t)(r0 + 32) * NE + nc + 64 + 4 * c4);
                s7 = *(const float4*)(nb + (size_t)(r0 + 48) * NE + nc + 64 + 4 * c4);
            } else {
                // issue stats (64 rows x 16 cols f32): all 256 threads, 1 float4
                s0 = *(const float4*)(st + (tid >> 2) * NS + (tid & 3) * 4);
            }
        } else {
            // write stats staged at ch==2 into cols 512..527
            *(half4_t*)&A[(tid >> 2) * AS + 512 + (tid & 3) * 4] = cvt4(s0);
        }
        asm volatile("s_waitcnt lgkmcnt(0)" ::: "memory");
        __builtin_amdgcn_sched_barrier(0);
        __builtin_amdgcn_s_barrier();
        __builtin_amdgcn_sched_barrier(0);
    }
    // K-tail: stats cols 512..527 (t = 32, loaded into bX at t=30)
    {
        half8_t a0 = *(const half8_t*)&Abase[512];
        half8_t a1 = *(const half8_t*)&Abase[32 * AS + 512];
        acc00 = __builtin_amdgcn_mfma_f32_32x32x16_f16(a0, bx0, acc00, 0, 0, 0);
        acc10 = __builtin_amdgcn_mfma_f32_32x32x16_f16(a1, bx0, acc10, 0, 0, 0);
        acc01 = __builtin_amdgcn_mfma_f32_32x32x16_f16(a0, bx1, acc01, 0, 0, 0);
        acc11 = __builtin_amdgcn_mfma_f32_32x32x16_f16(a1, bx1, acc11, 0, 0, 0);
        acc02 = __builtin_amdgcn_mfma_f32_32x32x16_f16(a0, bx2, acc02, 0, 0, 0);
        acc12 = __builtin_amdgcn_mfma_f32_32x32x16_f16(a1, bx2, acc12, 0, 0, 0);
        acc03 = __builtin_amdgcn_mfma_f32_32x32x16_f16(a0, bx3, acc03, 0, 0, 0);
        acc13 = __builtin_amdgcn_mfma_f32_32x32x16_f16(a1, bx3, acc13, 0, 0, 0);
    }

    // ---- epilogue: 8 tiles -> gelu, x sw2, col-reduce, Llds partials ----
    epi_one(acc00, qv0, w20, 0,  4 * w + 0, ln, hi, Llds);
    epi_one(acc01, qv1, w21, 0,  4 * w + 1, ln, hi, Llds);
    epi_one(acc02, qv2, w22, 0,  4 * w + 2, ln, hi, Llds);
    epi_one(acc03, qv3, w23, 0,  4 * w + 3, ln, hi, Llds);
    epi_one(acc10, qv0, w20, 32, 4 * w + 0, ln, hi, Llds);
    epi_one(acc11, qv1, w21, 32, 4 * w + 1, ln, hi, Llds);
    epi_one(acc12, qv2, w22, 32, 4 * w + 2, ln, hi, Llds);
    epi_one(acc13, qv3, w23, 32, 4 * w + 3, ln, hi, Llds);
    __syncthreads();   // Llds is cross-wave: barrier required

    // ---- softmax over K=64: ALL 4 waves redundantly; lane l owns k=l ----
    {
        int k = l;
        float lsum = 0.0f;
#pragma unroll
        for (int j = 0; j < 16; ++j) lsum += Llds[k][j];
        float sim = st[k * NS + (NS - 1)];
        float logit = lsum + sb2[0] + alpha[0] * sim;
        float mx = logit;
#pragma unroll
        for (int m = 1; m < 64; m <<= 1) mx = fmaxf(mx, __shfl_xor(mx, m, 64));
        float e = __expf(logit - mx);
        float s = e;
#pragma unroll
        for (int m = 1; m < 64; m <<= 1) s += __shfl_xor(s, m, 64);
        float at = e / s;
        attn_s[w][k] = at;                 // own wave's copy: DS in-order
        if (w == 0) attn_out[(size_t)b * NK + k] = at;
    }
    // NO barrier: each wave reads only its own attn_s[w] copy below.

    // ---- mix from LDS (half2 per thread): mixed[e'] = sum_k attn[k]*A[k][e'] ----
    {
        int c0 = 2 * tid;  // cols [c0, c0+1]: 256 threads cover 0..511
        float m0 = 0.0f, m1 = 0.0f;
#pragma unroll 8
        for (int k = 0; k < NK; ++k) {
            half2_t v = *(const half2_t*)&A[k * AS + c0];
            float aw = attn_s[w][k];
            m0 += aw * (float)v[0];
            m1 += aw * (float)v[1];
        }
        *(half2_t*)&mixed[(size_t)b * AS + c0] = (half2_t){(half_t)m0, (half_t)m1};
        if (tid < 8) {  // stats cols 512..527 (w==0 for these threads)
            int cs = 512 + 2 * tid;
            float n0 = 0.0f, n1 = 0.0f;
#pragma unroll 8
            for (int k = 0; k < NK; ++k) {
                half2_t v = *(const half2_t*)&A[k * AS + cs];
                float aw = attn_s[0][k];
                n0 += aw * (float)v[0];
                n1 += aw * (float)v[1];
            }
            *(half2_t*)&mixed[(size_t)b * AS + cs] = (half2_t){(half_t)n0, (half_t)n1};
        } else if (tid < 14) {
            int z = tid - 8;  // zero cols 528..551 (6 x half4)
            half4_t hz = {};
            *(half4_t*)&mixed[(size_t)b * AS + 528 + 4 * z] = hz;
        }
    }
}

// ---------------------------------------------------------------------------
// proj_kernel: out = gelu(mixed@pw1 + pb1) @ pw2 + pb2, both layers fused.
// 1024 threads = 16 waves (wave owns 32 cols) for better latency hiding.
__global__ __launch_bounds__(1024) void proj_kernel(
    const half_t* __restrict__ mixedp, const half_t* __restrict__ Wp1,
    const half_t* __restrict__ Wp2, const float* __restrict__ pb1,
    const float* __restrict__ pb2, float* __restrict__ out) {
    constexpr int AS3 = AS;
    __shared__ __align__(16) half_t A1[16 * AS3];
    int b0 = blockIdx.x * 16;
    int tid = threadIdx.x;
    const uint4* src = (const uint4*)(mixedp + (size_t)b0 * AS3);
    for (int i = tid; i < 1104; i += 1024) ((uint4*)A1)[i] = src[i];
    __syncthreads();

    int w = tid >> 6, l = tid & 63, lg = l >> 4, ln = l & 15;
    floatx4 acc[2] = { {0,0,0,0}, {0,0,0,0} };
    for (int t = 0; t < 17; ++t) {
        half8_t a = *(const half8_t*)&A1[ln * AS3 + t * 32 + 8 * lg];
#pragma unroll
        for (int ni = 0; ni < 2; ++ni) {
            int n = w * 32 + ni * 16 + ln;
            half8_t bf = *(const half8_t*)(Wp1 + ((size_t)t * NE + n) * 32 + 8 * lg);
            acc[ni] = __builtin_amdgcn_mfma_f32_16x16x32_f16(a, bf, acc[ni], 0, 0, 0);
        }
    }
    __syncthreads();
#pragma unroll
    for (int ni = 0; ni < 2; ++ni) {
        int col = w * 32 + ni * 16 + ln;
        float bias = pb1[col];
#pragma unroll
        for (int r = 0; r < 4; ++r) {
            int row = 4 * lg + r;
            A1[row * AS3 + col] = (half_t)gelu_erf(acc[ni][r] + bias);
        }
    }
    __syncthreads();
    floatx4 acc2[2] = { {0,0,0,0}, {0,0,0,0} };
    for (int t = 0; t < 16; ++t) {
        half8_t a = *(const half8_t*)&A1[ln * AS3 + t * 32 + 8 * lg];
#pragma unroll
        for (int ni = 0; ni < 2; ++ni) {
            int n = w * 32 + ni * 16 + ln;
            half8_t bf = *(const half8_t*)(Wp2 + ((size_t)t * NE + n) * 32 + 8 * lg);
            acc2[ni] = __builtin_amdgcn_mfma_f32_16x16x32_f16(a, bf, acc2[ni], 0, 0, 0);
        }
    }
#pragma unroll
    for (int ni = 0; ni < 2; ++ni) {
        int col = w * 32 + ni * 16 + ln;
        float bias = pb2[col];
#pragma unroll
        for (int r = 0; r < 4; ++r)
            out[(size_t)(b0 + 4 * lg + r) * NE + col] = acc2[ni][r] + bias;
    }
}

// ---------------------------------------------------------------------------
extern "C" void kernel_launch(void* const* d_in, const int* in_sizes, int n_in,
                              void* d_out, int out_size, void* d_ws, size_t ws_size,
                              hipStream_t stream) {
    (void)in_sizes; (void)n_in; (void)out_size; (void)ws_size;
    const float* q     = (const float*)d_in[0];
    const float* c     = (const float*)d_in[1];
    const float* nb    = (const float*)d_in[2];
    const float* st    = (const float*)d_in[3];
    const float* sw1   = (const float*)d_in[4];
    const float* sb1   = (const float*)d_in[5];
    const float* sw2   = (const float*)d_in[6];
    const float* sb2   = (const float*)d_in[7];
    const float* alpha = (const float*)d_in[8];
    const float* pw1   = (const float*)d_in[9];
    const float* pb1   = (const float*)d_in[10];
    const float* pw2   = (const float*)d_in[11];
    const float* pb2   = (const float*)d_in[12];

    char* ws = (char*)d_ws;
    half_t* Wq  = (half_t*)(ws + 0);          // 1024*512*2 = 1048576
    half_t* Wns = (half_t*)(ws + 1048576);    // 33*512*16*2 = 540672
    half_t* Wp1 = (half_t*)(ws + 1605632);    // 544*512*2  = 557056
    half_t* Wp2 = (half_t*)(ws + 2162688);    // 512*512*2  = 524288
    float*  qcb = (float*)(ws + 2686976);     // 2048*512*4 = 4194304
    half_t* mix = (half_t*)(ws + 6881280);    // 2048*552*2 = 2260992

    float* outp  = (float*)d_out;
    float* attnp = outp + (size_t)NBATCH * NE;

    pack_all<<<784, 256, 0, stream>>>(sw1, pw1, pw2, Wq, Wns, Wp1, Wp2);
    qc_kernel<<<256, 512, 0, stream>>>(q, c, Wq, sb1, qcb);
    main_kernel<<<2048, 256, 0, stream>>>(nb, st, Wns, qcb, sw2, sb2, alpha, attnp, mix);
    proj_kernel<<<128, 1024, 0, stream>>>(mix, Wp1, Wp2, pb1, pb2, outp);
}

// Round 6
// 169.975 us; speedup vs baseline: 1.0745x; 1.0556x over previous
//
#include <hip/hip_runtime.h>

typedef _Float16 half_t;
typedef _Float16 half2_t __attribute__((ext_vector_type(2)));
typedef _Float16 half4_t __attribute__((ext_vector_type(4)));
typedef _Float16 half8_t __attribute__((ext_vector_type(8)));
typedef float floatx4 __attribute__((ext_vector_type(4)));
typedef float floatx16 __attribute__((ext_vector_type(16)));

#define NE 512
#define NS 16
#define NBATCH 2048
#define NK 64
#define AS 552  // LDS row stride (halves)

// gelu(x) = 0.5 x (1 + erf(x/sqrt2)); erf via A&S 7.1.26 (|err|<=1.5e-7), branch-free.
__device__ __forceinline__ float gelu_erf(float x) {
    float z = x * 0.70710678118654752440f;
    float az2 = z * z;
    float az = __builtin_fabsf(z);
    float t = __builtin_amdgcn_rcpf(__builtin_fmaf(0.3275911f, az, 1.0f));
    float p = __builtin_fmaf(1.061405429f, t, -1.453152027f);
    p = __builtin_fmaf(p, t, 1.421413741f);
    p = __builtin_fmaf(p, t, -0.284496736f);
    p = __builtin_fmaf(p, t, 0.254829592f);
    p = p * t;
    float e = __expf(-az2);
    float erfa = __builtin_fmaf(-p, e, 1.0f);
    unsigned int u = __float_as_uint(erfa) ^ (__float_as_uint(z) & 0x80000000u);
    return 0.5f * x * (1.0f + __uint_as_float(u));
}

__device__ __forceinline__ half4_t cvt4(float4 v) {
    return (half4_t){(half_t)v.x, (half_t)v.y, (half_t)v.z, (half_t)v.w};
}

// packed 32-lane column reduction of 16 values: returns full col-sum of
// x[ln&15] at each lane (reduction over the 32-lane half).
__device__ __forceinline__ float colreduce16(const float (&x)[16], int lnb) {
    float y[8];
#pragma unroll
    for (int i = 0; i < 8; ++i) {
        float keep = (lnb & 1) ? x[2 * i + 1] : x[2 * i];
        float send = (lnb & 1) ? x[2 * i] : x[2 * i + 1];
        y[i] = keep + __shfl_xor(send, 1, 64);
    }
    float z[4];
#pragma unroll
    for (int i = 0; i < 4; ++i) {
        float keep = (lnb & 2) ? y[2 * i + 1] : y[2 * i];
        float send = (lnb & 2) ? y[2 * i] : y[2 * i + 1];
        z[i] = keep + __shfl_xor(send, 2, 64);
    }
    float u[2];
#pragma unroll
    for (int i = 0; i < 2; ++i) {
        float keep = (lnb & 4) ? z[2 * i + 1] : z[2 * i];
        float send = (lnb & 4) ? z[2 * i] : z[2 * i + 1];
        u[i] = keep + __shfl_xor(send, 4, 64);
    }
    float keep = (lnb & 8) ? u[1] : u[0];
    float send = (lnb & 8) ? u[0] : u[1];
    float v = keep + __shfl_xor(send, 8, 64);
    v += __shfl_xor(v, 16, 64);
    return v;
}

// ---------------------------------------------------------------------------
// pack bodies (device): 16x16x32 layout dst[(t*512+n)*32+kk] and 32x32x16
// layout dst[(t*512+n)*16+kk]. Shared tile passed in (max 32*68 halves).
__device__ void pack_w_body(const float* __restrict__ src, half_t* __restrict__ dst,
                            int Ksrc, int t, int nb0, half_t* tile) {
    int tid = threadIdx.x;
#pragma unroll
    for (int i = 0; i < 8; ++i) {
        int idx = tid + i * 256;
        int kk = idx >> 6, np = idx & 63;
        int k = t * 32 + kk;
        float v = (k < Ksrc) ? src[(size_t)k * NE + nb0 + np] : 0.0f;
        tile[kk * 68 + np] = (half_t)v;
    }
    __syncthreads();
#pragma unroll
    for (int i = 0; i < 8; ++i) {
        int idx = tid + i * 256;
        int np = idx >> 5, kk = idx & 31;
        dst[((size_t)t * NE + nb0 + np) * 32 + kk] = tile[kk * 68 + np];
    }
}

__device__ void pack_w32_body(const float* __restrict__ src, half_t* __restrict__ dst,
                              int Ksrc, int t, int nb0, half_t* tile) {
    int tid = threadIdx.x;
#pragma unroll
    for (int i = 0; i < 4; ++i) {
        int idx = tid + i * 256;
        int kk = idx >> 6, n = idx & 63;
        int k = t * 16 + kk;
        float v = (k < Ksrc) ? src[(size_t)k * NE + nb0 + n] : 0.0f;
        tile[kk * 68 + n] = (half_t)v;
    }
    __syncthreads();
    int n = threadIdx.x >> 2, q = threadIdx.x & 3;
    half4_t h = {tile[(q * 4) * 68 + n], tile[(q * 4 + 1) * 68 + n],
                 tile[(q * 4 + 2) * 68 + n], tile[(q * 4 + 3) * 68 + n]};
    *(half4_t*)&dst[((size_t)t * NE + nb0 + n) * 16 + q * 4] = h;
}

// pack_all: one launch does all four weight packs. Block ranges:
// [0,256) Wq | [256,520) Wns (32x32 layout) | [520,656) Wp1 | [656,784) Wp2.
__global__ __launch_bounds__(256) void pack_all(
    const float* __restrict__ sw1, const float* __restrict__ pw1,
    const float* __restrict__ pw2, half_t* __restrict__ Wq,
    half_t* __restrict__ Wns, half_t* __restrict__ Wp1, half_t* __restrict__ Wp2) {
    __shared__ half_t tile[32 * 68];
    int bx = blockIdx.x;
    if (bx < 256) {
        pack_w_body(sw1, Wq, 1024, bx >> 3, (bx & 7) * 64, tile);
    } else if (bx < 520) {
        int b2 = bx - 256;
        pack_w32_body(sw1 + (size_t)1024 * NE, Wns, 528, b2 >> 3, (b2 & 7) * 64, tile);
    } else if (bx < 656) {
        int b3 = bx - 520;
        pack_w_body(pw1, Wp1, 528, b3 >> 3, (b3 & 7) * 64, tile);
    } else {
        int b4 = bx - 656;
        pack_w_body(pw2, Wp2, 512, b4 >> 3, (b4 & 7) * 64, tile);
    }
}

// ---------------------------------------------------------------------------
// qc_kernel: qc[b,n] = q[b]@sw1[0:512] + c[b]@sw1[512:1024] + sb1[n].
// grid = 256: bx>>1 = 16-row group, bx&1 = 256-col half (all CUs busy).
__global__ __launch_bounds__(512) void qc_kernel(const float* __restrict__ q,
                                                 const float* __restrict__ c,
                                                 const half_t* __restrict__ Wq,
                                                 const float* __restrict__ sb1,
                                                 float* __restrict__ qcb) {
    constexpr int AS1 = 1032;
    __shared__ __align__(16) half_t A1[16 * AS1];
    int b0 = (blockIdx.x >> 1) * 16;
    int nh = (blockIdx.x & 1) * 256;
    int tid = threadIdx.x;
#pragma unroll
    for (int i = 0; i < 8; ++i) {
        int f = tid + i * 512;
        int row = f >> 8;
        int c4 = f & 255;
        const float* srcp = (c4 < 128) ? (q + (size_t)(b0 + row) * NE + c4 * 4)
                                       : (c + (size_t)(b0 + row) * NE + (c4 - 128) * 4);
        float4 v = *(const float4*)srcp;
        *(half4_t*)&A1[row * AS1 + c4 * 4] = cvt4(v);
    }
    __syncthreads();
    int w = tid >> 6, l = tid & 63, lg = l >> 4, ln = l & 15;
    floatx4 acc[2] = { {0,0,0,0}, {0,0,0,0} };
    for (int t = 0; t < 32; ++t) {
        half8_t a = *(const half8_t*)&A1[ln * AS1 + t * 32 + 8 * lg];
#pragma unroll
        for (int ni = 0; ni < 2; ++ni) {
            int n = nh + w * 32 + ni * 16 + ln;
            half8_t bf = *(const half8_t*)(Wq + ((size_t)t * NE + n) * 32 + 8 * lg);
            acc[ni] = __builtin_amdgcn_mfma_f32_16x16x32_f16(a, bf, acc[ni], 0, 0, 0);
        }
    }
#pragma unroll
    for (int ni = 0; ni < 2; ++ni) {
        int col = nh + w * 32 + ni * 16 + ln;
        float bias = sb1[col];
#pragma unroll
        for (int r = 0; r < 4; ++r) {
            int row = 4 * lg + r;
            qcb[(size_t)(b0 + row) * NE + col] = acc[ni][r] + bias;
        }
    }
}

// ---------------------------------------------------------------------------
// main_kernel v7 = v1 EXACTLY (proven 168us: full-resident A, 2 blocks/CU,
// 2-pass acc-32 -- the only vertex of the {acc x waves/SIMD x prefetch} budget
// triangle that fits 128 regs/wave without spilling; v2-v6 probed every other
// corner) + the two v4 changes that were NOT the spill (v4's regression was
// solely the bfr[8] hoist: +32 live regs across staging -> 64 MB scratch):
//  1. s_setprio(1)/(0) around every MFMA burst: the two co-resident blocks
//     drift out of phase, so SIMDs host {GEMM-phase, epilogue-phase} wave
//     mixes -- the regime where setprio arbitration pays (T5).
//  2. softmax sim column prefetched into Llds[.][16] (unused pad col) at the
//     prologue: removes an exposed global read behind the final barrier.
// B loads stay at v1's loop-top placement (the hoist is what spilled).
// Pass 1 = R8 FIFO-ordered stage-ahead-2 pipeline (register ceiling -- do not
// add live state). Pass 2 = 2-deep register double-buffered B. Tail: ALL
// waves compute softmax redundantly into per-wave attn copies (intra-wave DS
// ordering -> no final barrier); mix keeps LDS-broadcast reads.
__global__ __launch_bounds__(512, 4) void main_kernel(
    const float* __restrict__ neighbors, const float* __restrict__ stats,
    const half_t* __restrict__ Wns, const float* __restrict__ qcb,
    const float* __restrict__ sw2, const float* __restrict__ sb2,
    const float* __restrict__ alpha, float* __restrict__ attn_out,
    half_t* __restrict__ mixed) {
    __shared__ __align__(16) half_t A[64 * AS];  // 70656 B
    __shared__ float Llds[64][17];
    __shared__ float attn_s[8][64];              // per-wave copy: no tail barrier

    int b = blockIdx.x;
    int tid = threadIdx.x;
    const float* nb = neighbors + (size_t)b * NK * NE;
    const float* st = stats + (size_t)b * NK * NS;

    int r0 = tid >> 5;     // 0..15 (staging rows r0+16i)
    int c4 = tid & 31;     // float4-col within 128-col chunk
    int w = tid >> 6;      // wave 0..7
    int l = tid & 63, ln = l & 31, hi = l >> 5;
    const half_t* Abase = A + ln * AS + 8 * hi;
    const half_t* Wb = Wns + ((size_t)(w * 32 + ln)) * 16 + 8 * hi;  // + t*8192

    // ---- prologue: stage chunk 0; issue chunk 1; preload epilogue scalars;
    //      prefetch softmax sim column into the Llds pad col ----
    float4 s0, s1, s2, s3, sst;
    float qv1, w21, qv2, w22;
    {
        float4 p0 = *(const float4*)(nb + (size_t)(r0) * NE + 4 * c4);
        float4 p1 = *(const float4*)(nb + (size_t)(r0 + 16) * NE + 4 * c4);
        float4 p2 = *(const float4*)(nb + (size_t)(r0 + 32) * NE + 4 * c4);
        float4 p3 = *(const float4*)(nb + (size_t)(r0 + 48) * NE + 4 * c4);
        __builtin_amdgcn_sched_barrier(0);
        s0 = *(const float4*)(nb + (size_t)(r0) * NE + 128 + 4 * c4);
        s1 = *(const float4*)(nb + (size_t)(r0 + 16) * NE + 128 + 4 * c4);
        s2 = *(const float4*)(nb + (size_t)(r0 + 32) * NE + 128 + 4 * c4);
        s3 = *(const float4*)(nb + (size_t)(r0 + 48) * NE + 128 + 4 * c4);
        qv1 = qcb[(size_t)b * NE + w * 32 + ln];
        w21 = sw2[w * 32 + ln];
        qv2 = qcb[(size_t)b * NE + 256 + w * 32 + ln];
        w22 = sw2[256 + w * 32 + ln];
        __builtin_amdgcn_sched_barrier(0);
        *(half4_t*)&A[(r0) * AS + 4 * c4] = cvt4(p0);
        *(half4_t*)&A[(r0 + 16) * AS + 4 * c4] = cvt4(p1);
        *(half4_t*)&A[(r0 + 32) * AS + 4 * c4] = cvt4(p2);
        *(half4_t*)&A[(r0 + 48) * AS + 4 * c4] = cvt4(p3);
        // softmax sim column -> unused Llds pad col (read after final barrier)
        if (tid < 64) Llds[tid][16] = st[tid * NS + (NS - 1)];
    }
    asm volatile("s_waitcnt lgkmcnt(0)" ::: "memory");
    __builtin_amdgcn_sched_barrier(0);
    __builtin_amdgcn_s_barrier();
    __builtin_amdgcn_sched_barrier(0);

    floatx16 acc0 = {0,0,0,0,0,0,0,0,0,0,0,0,0,0,0,0};
    floatx16 acc1 = {0,0,0,0,0,0,0,0,0,0,0,0,0,0,0,0};

    // ---- pass 1, pipelined chunks 0..3 (8 K-steps of 16 each) ----
#pragma unroll 1
    for (int ch = 0; ch < 4; ++ch) {
        half8_t bfr[8];
#pragma unroll
        for (int s8 = 0; s8 < 8; ++s8)
            bfr[s8] = *(const half8_t*)(Wb + (size_t)(ch * 8 + s8) * 8192);
        __builtin_amdgcn_sched_barrier(0);
        float4 n0, n1, n2, n3;
        if (ch < 2) {
            n0 = *(const float4*)(nb + (size_t)(r0) * NE + (ch + 2) * 128 + 4 * c4);
            n1 = *(const float4*)(nb + (size_t)(r0 + 16) * NE + (ch + 2) * 128 + 4 * c4);
            n2 = *(const float4*)(nb + (size_t)(r0 + 32) * NE + (ch + 2) * 128 + 4 * c4);
            n3 = *(const float4*)(nb + (size_t)(r0 + 48) * NE + (ch + 2) * 128 + 4 * c4);
        } else if (ch == 2) {
            if (tid < 256)
                sst = *(const float4*)(st + (tid >> 2) * NS + (tid & 3) * 4);
        }
        __builtin_amdgcn_sched_barrier(0);
        __builtin_amdgcn_s_setprio(1);
#pragma unroll
        for (int s8 = 0; s8 < 8; ++s8) {
            int col = ch * 128 + s8 * 16;
            half8_t a0 = *(const half8_t*)&Abase[col];
            half8_t a1 = *(const half8_t*)&Abase[32 * AS + col];
            acc0 = __builtin_amdgcn_mfma_f32_32x32x16_f16(a0, bfr[s8], acc0, 0, 0, 0);
            acc1 = __builtin_amdgcn_mfma_f32_32x32x16_f16(a1, bfr[s8], acc1, 0, 0, 0);
        }
        __builtin_amdgcn_s_setprio(0);
        if (ch < 3) {
            *(half4_t*)&A[(r0) * AS + (ch + 1) * 128 + 4 * c4] = cvt4(s0);
            *(half4_t*)&A[(r0 + 16) * AS + (ch + 1) * 128 + 4 * c4] = cvt4(s1);
            *(half4_t*)&A[(r0 + 32) * AS + (ch + 1) * 128 + 4 * c4] = cvt4(s2);
            *(half4_t*)&A[(r0 + 48) * AS + (ch + 1) * 128 + 4 * c4] = cvt4(s3);
            s0 = n0; s1 = n1; s2 = n2; s3 = n3;
        } else {
            if (tid < 256)
                *(half4_t*)&A[(tid >> 2) * AS + 512 + (tid & 3) * 4] = cvt4(sst);
        }
        asm volatile("s_waitcnt lgkmcnt(0)" ::: "memory");
        __builtin_amdgcn_sched_barrier(0);
        __builtin_amdgcn_s_barrier();
        __builtin_amdgcn_sched_barrier(0);
    }
    // final K-step of pass 1 (stats cols 512..527, t = 32)
    {
        half8_t bfa = *(const half8_t*)(Wb + (size_t)32 * 8192);
        half8_t a0 = *(const half8_t*)&Abase[512];
        half8_t a1 = *(const half8_t*)&Abase[32 * AS + 512];
        __builtin_amdgcn_s_setprio(1);
        acc0 = __builtin_amdgcn_mfma_f32_32x32x16_f16(a0, bfa, acc0, 0, 0, 0);
        acc1 = __builtin_amdgcn_mfma_f32_32x32x16_f16(a1, bfa, acc1, 0, 0, 0);
        __builtin_amdgcn_s_setprio(0);
    }

    // ---- prime pass-2 first two B pairs (latency hides under epilogue-1) ----
    const half_t* Wb2 = Wb + 4096;  // cols +256
    half8_t pA0 = *(const half8_t*)(Wb2);
    half8_t pB0 = *(const half8_t*)(Wb2 + 8192);
    half8_t pA1 = *(const half8_t*)(Wb2 + 2 * 8192);
    half8_t pB1 = *(const half8_t*)(Wb2 + 3 * 8192);
    __builtin_amdgcn_sched_barrier(0);

    // ---- epilogue pass 1 ----
    {
        float g0[16], g1[16];
#pragma unroll
        for (int r = 0; r < 16; ++r) {
            g0[r] = gelu_erf(acc0[r] + qv1) * w21;
            g1[r] = gelu_erf(acc1[r] + qv1) * w21;
        }
        float rA = colreduce16(g0, ln);
        float rB = colreduce16(g1, ln);
        if (ln < 16) {
            int row = (ln & 3) + 8 * (ln >> 2) + 4 * hi;
            Llds[row][w] = rA;
            Llds[32 + row][w] = rB;
        }
    }

    // ---- pass 2: cols 256..511 over k 0..527, 2-deep double-buffered B ----
    acc0 = (floatx16){0,0,0,0,0,0,0,0,0,0,0,0,0,0,0,0};
    acc1 = (floatx16){0,0,0,0,0,0,0,0,0,0,0,0,0,0,0,0};
#pragma unroll 1
    for (int t2 = 0; t2 < 16; ++t2) {
        int tn = 2 * t2 + 4;
        if (tn > 32) tn = 32;
        int tn1 = tn + 1;
        if (tn1 > 32) tn1 = 32;   // never touch t=33 (doesn't exist)
        half8_t nA = *(const half8_t*)(Wb2 + (size_t)tn * 8192);
        half8_t nB = *(const half8_t*)(Wb2 + (size_t)tn1 * 8192);
        int col = t2 * 32;
        half8_t a0 = *(const half8_t*)&Abase[col];
        half8_t a1 = *(const half8_t*)&Abase[32 * AS + col];
        __builtin_amdgcn_s_setprio(1);
        acc0 = __builtin_amdgcn_mfma_f32_32x32x16_f16(a0, pA0, acc0, 0, 0, 0);
        acc1 = __builtin_amdgcn_mfma_f32_32x32x16_f16(a1, pA0, acc1, 0, 0, 0);
        half8_t a0b = *(const half8_t*)&Abase[col + 16];
        half8_t a1b = *(const half8_t*)&Abase[32 * AS + col + 16];
        acc0 = __builtin_amdgcn_mfma_f32_32x32x16_f16(a0b, pB0, acc0, 0, 0, 0);
        acc1 = __builtin_amdgcn_mfma_f32_32x32x16_f16(a1b, pB0, acc1, 0, 0, 0);
        __builtin_amdgcn_s_setprio(0);
        pA0 = pA1; pB0 = pB1; pA1 = nA; pB1 = nB;
    }
    // pass-2 K-tail: stats cols 512..527 (t = 32, now in pA0)
    {
        half8_t a0 = *(const half8_t*)&Abase[512];
        half8_t a1 = *(const half8_t*)&Abase[32 * AS + 512];
        __builtin_amdgcn_s_setprio(1);
        acc0 = __builtin_amdgcn_mfma_f32_32x32x16_f16(a0, pA0, acc0, 0, 0, 0);
        acc1 = __builtin_amdgcn_mfma_f32_32x32x16_f16(a1, pA0, acc1, 0, 0, 0);
        __builtin_amdgcn_s_setprio(0);
    }

    // ---- epilogue pass 2 ----
    {
        float g0[16], g1[16];
#pragma unroll
        for (int r = 0; r < 16; ++r) {
            g0[r] = gelu_erf(acc0[r] + qv2) * w22;
            g1[r] = gelu_erf(acc1[r] + qv2) * w22;
        }
        float rA = colreduce16(g0, ln);
        float rB = colreduce16(g1, ln);
        if (ln < 16) {
            int row = (ln & 3) + 8 * (ln >> 2) + 4 * hi;
            Llds[row][8 + w] = rA;
            Llds[32 + row][8 + w] = rB;
        }
    }
    __syncthreads();   // Llds is cross-wave: barrier required

    // ---- softmax over K=64: ALL waves redundantly; lane l owns k=l ----
    {
        int k = l;
        float lsum = 0.0f;
#pragma unroll
        for (int j = 0; j < 16; ++j) lsum += Llds[k][j];
        float sim = Llds[k][16];   // prefetched at prologue
        float logit = lsum + sb2[0] + alpha[0] * sim;
        float mx = logit;
#pragma unroll
        for (int m = 1; m < 64; m <<= 1) mx = fmaxf(mx, __shfl_xor(mx, m, 64));
        float e = __expf(logit - mx);
        float s = e;
#pragma unroll
        for (int m = 1; m < 64; m <<= 1) s += __shfl_xor(s, m, 64);
        float at = e / s;
        attn_s[w][k] = at;                 // own wave's copy: DS in-order
        if (w == 0) attn_out[(size_t)b * NK + k] = at;
    }
    // NO barrier: each wave reads only its own attn_s[w] copy below.

    // ---- mix from LDS (half2 per thread): mixed[e'] = sum_k attn[k]*A[k][e'] ----
    if (tid < 264) {
        int c0 = 2 * tid;  // cols [c0, c0+1], covers 0..527 (real data only)
        float m0 = 0.0f, m1 = 0.0f;
#pragma unroll 8
        for (int k = 0; k < NK; ++k) {
            half2_t v = *(const half2_t*)&A[k * AS + c0];
            float aw = attn_s[w][k];
            m0 += aw * (float)v[0];
            m1 += aw * (float)v[1];
        }
        *(half2_t*)&mixed[(size_t)b * AS + c0] = (half2_t){(half_t)m0, (half_t)m1};
    } else if (tid < 270) {
        int z = tid - 264;  // zero cols 528..551 (6 x half4)
        half4_t hz = {};
        *(half4_t*)&mixed[(size_t)b * AS + 528 + 4 * z] = hz;
    }
}

// ---------------------------------------------------------------------------
// proj_kernel: out = gelu(mixed@pw1 + pb1) @ pw2 + pb2, both layers fused.
// 1024 threads = 16 waves (wave owns 32 cols) for better latency hiding.
__global__ __launch_bounds__(1024) void proj_kernel(
    const half_t* __restrict__ mixedp, const half_t* __restrict__ Wp1,
    const half_t* __restrict__ Wp2, const float* __restrict__ pb1,
    const float* __restrict__ pb2, float* __restrict__ out) {
    constexpr int AS3 = AS;
    __shared__ __align__(16) half_t A1[16 * AS3];
    int b0 = blockIdx.x * 16;
    int tid = threadIdx.x;
    const uint4* src = (const uint4*)(mixedp + (size_t)b0 * AS3);
    for (int i = tid; i < 1104; i += 1024) ((uint4*)A1)[i] = src[i];
    __syncthreads();

    int w = tid >> 6, l = tid & 63, lg = l >> 4, ln = l & 15;
    floatx4 acc[2] = { {0,0,0,0}, {0,0,0,0} };
    for (int t = 0; t < 17; ++t) {
        half8_t a = *(const half8_t*)&A1[ln * AS3 + t * 32 + 8 * lg];
#pragma unroll
        for (int ni = 0; ni < 2; ++ni) {
            int n = w * 32 + ni * 16 + ln;
            half8_t bf = *(const half8_t*)(Wp1 + ((size_t)t * NE + n) * 32 + 8 * lg);
            acc[ni] = __builtin_amdgcn_mfma_f32_16x16x32_f16(a, bf, acc[ni], 0, 0, 0);
        }
    }
    __syncthreads();
#pragma unroll
    for (int ni = 0; ni < 2; ++ni) {
        int col = w * 32 + ni * 16 + ln;
        float bias = pb1[col];
#pragma unroll
        for (int r = 0; r < 4; ++r) {
            int row = 4 * lg + r;
            A1[row * AS3 + col] = (half_t)gelu_erf(acc[ni][r] + bias);
        }
    }
    __syncthreads();
    floatx4 acc2[2] = { {0,0,0,0}, {0,0,0,0} };
    for (int t = 0; t < 16; ++t) {
        half8_t a = *(const half8_t*)&A1[ln * AS3 + t * 32 + 8 * lg];
#pragma unroll
        for (int ni = 0; ni < 2; ++ni) {
            int n = w * 32 + ni * 16 + ln;
            half8_t bf = *(const half8_t*)(Wp2 + ((size_t)t * NE + n) * 32 + 8 * lg);
            acc2[ni] = __builtin_amdgcn_mfma_f32_16x16x32_f16(a, bf, acc2[ni], 0, 0, 0);
        }
    }
#pragma unroll
    for (int ni = 0; ni < 2; ++ni) {
        int col = w * 32 + ni * 16 + ln;
        float bias = pb2[col];
#pragma unroll
        for (int r = 0; r < 4; ++r)
            out[(size_t)(b0 + 4 * lg + r) * NE + col] = acc2[ni][r] + bias;
    }
}

// ---------------------------------------------------------------------------
extern "C" void kernel_launch(void* const* d_in, const int* in_sizes, int n_in,
                              void* d_out, int out_size, void* d_ws, size_t ws_size,
                              hipStream_t stream) {
    (void)in_sizes; (void)n_in; (void)out_size; (void)ws_size;
    const float* q     = (const float*)d_in[0];
    const float* c     = (const float*)d_in[1];
    const float* nb    = (const float*)d_in[2];
    const float* st    = (const float*)d_in[3];
    const float* sw1   = (const float*)d_in[4];
    const float* sb1   = (const float*)d_in[5];
    const float* sw2   = (const float*)d_in[6];
    const float* sb2   = (const float*)d_in[7];
    const float* alpha = (const float*)d_in[8];
    const float* pw1   = (const float*)d_in[9];
    const float* pb1   = (const float*)d_in[10];
    const float* pw2   = (const float*)d_in[11];
    const float* pb2   = (const float*)d_in[12];

    char* ws = (char*)d_ws;
    half_t* Wq  = (half_t*)(ws + 0);          // 1024*512*2 = 1048576
    half_t* Wns = (half_t*)(ws + 1048576);    // 33*512*16*2 = 540672
    half_t* Wp1 = (half_t*)(ws + 1605632);    // 544*512*2  = 557056
    half_t* Wp2 = (half_t*)(ws + 2162688);    // 512*512*2  = 524288
    float*  qcb = (float*)(ws + 2686976);     // 2048*512*4 = 4194304
    half_t* mix = (half_t*)(ws + 6881280);    // 2048*552*2 = 2260992

    float* outp  = (float*)d_out;
    float* attnp = outp + (size_t)NBATCH * NE;

    pack_all<<<784, 256, 0, stream>>>(sw1, pw1, pw2, Wq, Wns, Wp1, Wp2);
    qc_kernel<<<256, 512, 0, stream>>>(q, c, Wq, sb1, qcb);
    main_kernel<<<2048, 512, 0, stream>>>(nb, st, Wns, qcb, sw2, sb2, alpha, attnp, mix);
    proj_kernel<<<128, 1024, 0, stream>>>(mix, Wp1, Wp2, pb1, pb2, outp);
}